// Round 1
// baseline (7317.462 us; speedup 1.0000x reference)
//
#include <hip/hip_runtime.h>

#define HID  100
#define G4   400     // 4*HID
#define TENC 4096
#define TDEC 4096
#define NCLS 6
#define LG0  448     // first logits thread (wave 7 — no matvec rows, keeps SIMD issue balanced)

__device__ __forceinline__ float sigm(float v)  { return __builtin_amdgcn_rcpf(1.0f + __expf(-v)); }
__device__ __forceinline__ float tanh_(float v) { return 1.0f - 2.0f * __builtin_amdgcn_rcpf(1.0f + __expf(2.0f * v)); }

// Single persistent workgroup: one CU runs the whole recurrence.
// - thread t<400 owns gate row t: Whh row in VGPRs, computes + activates gate t
// - thread j<100 owns cell state c[j] in a register across all 8191 steps
// - h lives in LDS (broadcast reads, conflict-free)
// - threads 448..453 compute logits for the PREVIOUS h, overlapped with the matvec
__global__ __launch_bounds__(512, 1)
void lstm_seq(const float* __restrict__ x,      // [TENC*3]
              const int*   __restrict__ y,      // [TDEC]
              const float* __restrict__ eWih,   // [G4*3]
              const float* __restrict__ eWhh,   // [G4*HID]
              const float* __restrict__ ebih,   // [G4]
              const float* __restrict__ ebhh,   // [G4]
              const float* __restrict__ dWih,   // [G4]
              const float* __restrict__ dWhh,   // [G4*HID]
              const float* __restrict__ dbih,   // [G4]
              const float* __restrict__ dbhh,   // [G4]
              const float* __restrict__ linW,   // [NCLS*HID]
              const float* __restrict__ linb,   // [NCLS]
              float* __restrict__ out)          // [TDEC*NCLS]
{
    __shared__ __align__(16) float h_lds[HID];
    __shared__ float act[G4];

    const int t = threadIdx.x;
    const bool is_row   = (t < G4);
    const bool is_logit = (t >= LG0 && t < LG0 + NCLS);

    float w[HID];          // Whh row (enc, later dec) or lin_W row — stays in VGPRs
    float c = 0.0f;        // cell state for thread t<HID

    if (is_row) {
        #pragma unroll
        for (int k = 0; k < HID; ++k) w[k] = eWhh[t * HID + k];
    } else if (is_logit) {
        #pragma unroll
        for (int k = 0; k < HID; ++k) w[k] = linW[(t - LG0) * HID + k];
    } else {
        #pragma unroll
        for (int k = 0; k < HID; ++k) w[k] = 0.0f;
    }

    float ex0 = 0.f, ex1 = 0.f, ex2 = 0.f, eb = 0.f;
    if (is_row) {
        ex0 = eWih[t * 3 + 0]; ex1 = eWih[t * 3 + 1]; ex2 = eWih[t * 3 + 2];
        eb  = ebih[t] + ebhh[t];   // gx includes bih; fold bhh too
    }

    if (t < HID) h_lds[t] = 0.0f;   // h0 = 0
    __syncthreads();

    const float4* h4 = (const float4*)h_lds;

    // ---------------- encoder: 4096 steps ----------------
    float x0 = x[0], x1 = x[1], x2 = x[2];          // prefetch step 0 (wave-uniform -> s_load)
    for (int step = 0; step < TENC; ++step) {
        const float cx0 = x0, cx1 = x1, cx2 = x2;
        if (step + 1 < TENC) {                       // prefetch next step's x
            x0 = x[(step + 1) * 3 + 0];
            x1 = x[(step + 1) * 3 + 1];
            x2 = x[(step + 1) * 3 + 2];
        }
        if (is_row) {
            float a0 = eb + cx0 * ex0;
            float a1 = cx1 * ex1;
            float a2 = cx2 * ex2;
            float a3 = 0.0f;
            #pragma unroll
            for (int q = 0; q < HID / 4; ++q) {      // 25x ds_read_b128 + 100 fmac, 4 acc chains
                const float4 hv = h4[q];
                a0 += w[4 * q + 0] * hv.x;
                a1 += w[4 * q + 1] * hv.y;
                a2 += w[4 * q + 2] * hv.z;
                a3 += w[4 * q + 3] * hv.w;
            }
            const float g = (a0 + a1) + (a2 + a3);
            act[t] = (t < 2 * HID || t >= 3 * HID) ? sigm(g) : tanh_(g);  // i,f,o sigmoid; g tanh
        }
        __syncthreads();
        if (t < HID) {
            const float i = act[t], f = act[t + HID], gg = act[t + 2 * HID], o = act[t + 3 * HID];
            c = f * c + i * gg;
            h_lds[t] = o * tanh_(c);
        }
        __syncthreads();
    }

    // ---------------- swap weights to decoder ----------------
    if (is_row) {
        #pragma unroll
        for (int k = 0; k < HID; ++k) w[k] = dWhh[t * HID + k];
    }
    float dwt = 0.f, db = 0.f;
    if (is_row) { dwt = dWih[t]; db = dbih[t] + dbhh[t]; }
    const float lb = is_logit ? linb[t - LG0] : 0.0f;

    // ---------------- decoder: 4095 steps (teacher forcing: ratio==1 => u_t<1 always) ----------------
    float yf = (float)y[0];
    for (int step = 0; step < TDEC - 1; ++step) {
        const float cur_in = yf;
        if (step + 1 < TDEC - 1) yf = (float)y[step + 1];   // prefetch next input label
        if (is_row) {
            float a0 = db + cur_in * dwt;
            float a1 = 0.f, a2 = 0.f, a3 = 0.f;
            #pragma unroll
            for (int q = 0; q < HID / 4; ++q) {
                const float4 hv = h4[q];
                a0 += w[4 * q + 0] * hv.x;
                a1 += w[4 * q + 1] * hv.y;
                a2 += w[4 * q + 2] * hv.z;
                a3 += w[4 * q + 3] * hv.w;
            }
            const float g = (a0 + a1) + (a2 + a3);
            act[t] = (t < 2 * HID || t >= 3 * HID) ? sigm(g) : tanh_(g);
        } else if (is_logit && step > 0) {
            // logits for step-1 from h_lds (still holds h_{step-1}) — overlapped with matvec
            float a0 = lb, a1 = 0.f, a2 = 0.f, a3 = 0.f;
            #pragma unroll
            for (int q = 0; q < HID / 4; ++q) {
                const float4 hv = h4[q];
                a0 += w[4 * q + 0] * hv.x;
                a1 += w[4 * q + 1] * hv.y;
                a2 += w[4 * q + 2] * hv.z;
                a3 += w[4 * q + 3] * hv.w;
            }
            out[(step - 1) * NCLS + (t - LG0)] = (a0 + a1) + (a2 + a3);
        }
        __syncthreads();
        if (t < HID) {
            const float i = act[t], f = act[t + HID], gg = act[t + 2 * HID], o = act[t + 3 * HID];
            c = f * c + i * gg;
            h_lds[t] = o * tanh_(c);
        }
        __syncthreads();
    }

    // final logits row (TDEC-2) from the last h; zero the last out row (harness poisons d_out)
    if (is_logit) {
        float a0 = lb, a1 = 0.f, a2 = 0.f, a3 = 0.f;
        #pragma unroll
        for (int q = 0; q < HID / 4; ++q) {
            const float4 hv = h4[q];
            a0 += w[4 * q + 0] * hv.x;
            a1 += w[4 * q + 1] * hv.y;
            a2 += w[4 * q + 2] * hv.z;
            a3 += w[4 * q + 3] * hv.w;
        }
        out[(TDEC - 2) * NCLS + (t - LG0)] = (a0 + a1) + (a2 + a3);
    }
    if (t < NCLS) out[(TDEC - 1) * NCLS + t] = 0.0f;
}

extern "C" void kernel_launch(void* const* d_in, const int* in_sizes, int n_in,
                              void* d_out, int out_size, void* d_ws, size_t ws_size,
                              hipStream_t stream)
{
    const float* x    = (const float*)d_in[0];
    const int*   y    = (const int*)  d_in[1];
    const float* eWih = (const float*)d_in[2];
    const float* eWhh = (const float*)d_in[3];
    const float* ebih = (const float*)d_in[4];
    const float* ebhh = (const float*)d_in[5];
    const float* dWih = (const float*)d_in[6];
    const float* dWhh = (const float*)d_in[7];
    const float* dbih = (const float*)d_in[8];
    const float* dbhh = (const float*)d_in[9];
    const float* linW = (const float*)d_in[10];
    const float* linb = (const float*)d_in[11];
    float* out = (float*)d_out;

    lstm_seq<<<dim3(1), dim3(512), 0, stream>>>(
        x, y, eWih, eWhh, ebih, ebhh, dWih, dWhh, dbih, dbhh, linW, linb, out);
}

// Round 2
// 5444.653 us; speedup vs baseline: 1.3440x; 1.3440x over previous
//
#include <hip/hip_runtime.h>

typedef _Float16 h2_t __attribute__((ext_vector_type(2)));

#define HID  100
#define TENC 4096
#define TDEC 4096
#define NCLS 6

__device__ __forceinline__ float sigm(float v)  { return __builtin_amdgcn_rcpf(1.0f + __expf(-v)); }
__device__ __forceinline__ float tanh_(float v) { return 1.0f - 2.0f * __builtin_amdgcn_rcpf(1.0f + __expf(2.0f * v)); }

// Persistent single-workgroup recurrence. Thread layout: 128 threads = 2 waves;
// lanes 0..49 of each wave are workers -> 100 workers, worker `cell` owns LSTM
// cell `cell` completely: all 4 gate rows of Whh in packed-f16 VGPRs (208 regs),
// c in a register, activations local. h is broadcast via LDS (double-buffered,
// packed f16, padded to 13 float4 so every read is ds_read_b128).
// One __syncthreads per step. Decoder h is streamed to global (no dependent
// read -> fire-and-forget); logits are computed by a second parallel kernel.
__global__ __launch_bounds__(128, 1)
void lstm_rec(const float* __restrict__ x,      // [TENC*3]
              const int*   __restrict__ y,      // [TDEC]
              const float* __restrict__ eWih,   // [400*3]
              const float* __restrict__ eWhh,   // [400*HID]
              const float* __restrict__ ebih,
              const float* __restrict__ ebhh,
              const float* __restrict__ dWih,   // [400]
              const float* __restrict__ dWhh,
              const float* __restrict__ dbih,
              const float* __restrict__ dbhh,
              float* __restrict__ hsto)         // [ (TDEC-1) * HID ] decoder h history
{
    __shared__ __align__(16) _Float16 hbuf[2][112];   // 100 f16 + zero pad to 13 float4

    const int t    = threadIdx.x;
    const int ln   = t & 63;
    const int cell = (t >> 6) * 50 + ln;   // wave0 -> cells 0..49, wave1 -> cells 50..99
    const bool wk  = (ln < 50);

    h2_t  w[4][52];                        // 4 gate rows, k packed in f16 pairs (pad k=100..103 zero)
    float wx0[4], wx1[4], wx2[4], bs[4];
    float c = 0.0f;

    if (t < 112) { hbuf[0][t] = (_Float16)0.0f; hbuf[1][t] = (_Float16)0.0f; }

    if (wk) {
        #pragma unroll
        for (int r = 0; r < 4; ++r) {
            const int row = cell + r * HID;
            #pragma unroll
            for (int q = 0; q < 50; ++q) {
                w[r][q][0] = (_Float16)eWhh[row * HID + 2 * q];
                w[r][q][1] = (_Float16)eWhh[row * HID + 2 * q + 1];
            }
            w[r][50][0] = (_Float16)0.0f; w[r][50][1] = (_Float16)0.0f;
            w[r][51][0] = (_Float16)0.0f; w[r][51][1] = (_Float16)0.0f;
            wx0[r] = eWih[row * 3 + 0];
            wx1[r] = eWih[row * 3 + 1];
            wx2[r] = eWih[row * 3 + 2];
            bs[r]  = ebih[row] + ebhh[row];
        }
    }
    __syncthreads();

    int p = 0;

    // ---------------- encoder: 4096 steps ----------------
    float x0 = x[0], x1 = x[1], x2 = x[2];
    for (int s = 0; s < TENC; ++s) {
        const float cx0 = x0, cx1 = x1, cx2 = x2;
        if (s + 1 < TENC) { x0 = x[3*s+3]; x1 = x[3*s+4]; x2 = x[3*s+5]; }  // prefetch
        if (wk) {
            const float4* h4 = (const float4*)&hbuf[p][0];
            float a[4];
            #pragma unroll
            for (int r = 0; r < 4; ++r)
                a[r] = bs[r] + cx0 * wx0[r] + cx1 * wx1[r] + cx2 * wx2[r];
            #pragma unroll
            for (int q = 0; q < 13; ++q) {
                const float4 hv = h4[q];
                h2_t hh[4];
                hh[0] = __builtin_bit_cast(h2_t, hv.x);
                hh[1] = __builtin_bit_cast(h2_t, hv.y);
                hh[2] = __builtin_bit_cast(h2_t, hv.z);
                hh[3] = __builtin_bit_cast(h2_t, hv.w);
                #pragma unroll
                for (int m = 0; m < 4; ++m)
                    #pragma unroll
                    for (int r = 0; r < 4; ++r)
                        a[r] = __builtin_amdgcn_fdot2(w[r][4*q + m], hh[m], a[r], false);
            }
            const float fi = sigm(a[0]);
            const float ff = sigm(a[1]);
            const float fg = tanh_(a[2]);
            const float fo = sigm(a[3]);
            c = ff * c + fi * fg;
            const float hn = fo * tanh_(c);
            hbuf[p ^ 1][cell] = (_Float16)hn;
        }
        __syncthreads();
        p ^= 1;
    }

    // ---------------- swap to decoder weights ----------------
    float wxd[4], bsd[4];
    if (wk) {
        #pragma unroll
        for (int r = 0; r < 4; ++r) {
            const int row = cell + r * HID;
            #pragma unroll
            for (int q = 0; q < 50; ++q) {
                w[r][q][0] = (_Float16)dWhh[row * HID + 2 * q];
                w[r][q][1] = (_Float16)dWhh[row * HID + 2 * q + 1];
            }
            wxd[r] = dWih[row];
            bsd[r] = dbih[row] + dbhh[row];
        }
    }

    // ---------------- decoder: 4095 steps (ratio==1 -> always teacher-forced) ----------------
    float yin = (float)y[0];
    for (int s = 0; s < TDEC - 1; ++s) {
        const float cin = yin;
        if (s + 2 < TDEC) yin = (float)y[s + 1];   // prefetch next label
        if (wk) {
            const float4* h4 = (const float4*)&hbuf[p][0];
            float a[4];
            #pragma unroll
            for (int r = 0; r < 4; ++r)
                a[r] = bsd[r] + cin * wxd[r];
            #pragma unroll
            for (int q = 0; q < 13; ++q) {
                const float4 hv = h4[q];
                h2_t hh[4];
                hh[0] = __builtin_bit_cast(h2_t, hv.x);
                hh[1] = __builtin_bit_cast(h2_t, hv.y);
                hh[2] = __builtin_bit_cast(h2_t, hv.z);
                hh[3] = __builtin_bit_cast(h2_t, hv.w);
                #pragma unroll
                for (int m = 0; m < 4; ++m)
                    #pragma unroll
                    for (int r = 0; r < 4; ++r)
                        a[r] = __builtin_amdgcn_fdot2(w[r][4*q + m], hh[m], a[r], false);
            }
            const float fi = sigm(a[0]);
            const float ff = sigm(a[1]);
            const float fg = tanh_(a[2]);
            const float fo = sigm(a[3]);
            c = ff * c + fi * fg;
            const float hn = fo * tanh_(c);
            hbuf[p ^ 1][cell] = (_Float16)hn;
            hsto[s * HID + cell] = hn;             // fp32 h history; no dependent read in-kernel
        }
        __syncthreads();
        p ^= 1;
    }
}

// Parallel logits: out[t][r] = linW[r] . h_t + linb[r] for t in [0, TDEC-1),
// last row zeroed (harness poisons d_out).
__global__ __launch_bounds__(256)
void logits_k(const float* __restrict__ hsto, const float* __restrict__ linW,
              const float* __restrict__ linb, float* __restrict__ out)
{
    const int idx = blockIdx.x * 256 + threadIdx.x;
    if (idx >= TDEC * NCLS) return;
    const int tt = idx / NCLS;
    const int r  = idx % NCLS;
    if (tt >= TDEC - 1) { out[idx] = 0.0f; return; }
    const float* h  = hsto + tt * HID;
    const float* wr = linW + r * HID;
    float a = linb[r];
    #pragma unroll 4
    for (int k = 0; k < HID; ++k) a += wr[k] * h[k];
    out[idx] = a;
}

extern "C" void kernel_launch(void* const* d_in, const int* in_sizes, int n_in,
                              void* d_out, int out_size, void* d_ws, size_t ws_size,
                              hipStream_t stream)
{
    const float* x    = (const float*)d_in[0];
    const int*   y    = (const int*)  d_in[1];
    const float* eWih = (const float*)d_in[2];
    const float* eWhh = (const float*)d_in[3];
    const float* ebih = (const float*)d_in[4];
    const float* ebhh = (const float*)d_in[5];
    const float* dWih = (const float*)d_in[6];
    const float* dWhh = (const float*)d_in[7];
    const float* dbih = (const float*)d_in[8];
    const float* dbhh = (const float*)d_in[9];
    const float* linW = (const float*)d_in[10];
    const float* linb = (const float*)d_in[11];
    float* out  = (float*)d_out;
    float* hsto = (float*)d_ws;   // (TDEC-1)*HID*4 = 1.64 MB scratch

    lstm_rec<<<dim3(1), dim3(128), 0, stream>>>(
        x, y, eWih, eWhh, ebih, ebhh, dWih, dWhh, dbih, dbhh, hsto);

    const int nout = TDEC * NCLS;
    logits_k<<<dim3((nout + 255) / 256), dim3(256), 0, stream>>>(hsto, linW, linb, out);
}

// Round 3
// 5403.114 us; speedup vs baseline: 1.3543x; 1.0077x over previous
//
#include <hip/hip_runtime.h>

typedef _Float16 h2_t __attribute__((ext_vector_type(2)));

#define HID  100
#define TENC 4096
#define TDEC 4096
#define NCLS 6

__device__ __forceinline__ float sigm(float v)  { return __builtin_amdgcn_rcpf(1.0f + __expf(-v)); }
__device__ __forceinline__ float tanh_(float v) { return 1.0f - 2.0f * __builtin_amdgcn_rcpf(1.0f + __expf(2.0f * v)); }

// Persistent single-workgroup recurrence. 128 threads = 2 waves; lanes 0..49 of
// each wave are workers -> 100 workers. Worker `cell` owns LSTM cell `cell`:
// all 4 gate rows of Whh packed f16 in VGPRs (208 regs, pinned via asm so the
// compiler can't demote to scratch or re-load from global each step — R2's
// VGPR_Count=148 proved exactly that happened), c in a register, activations
// local. h broadcast via LDS (double-buffered f16, padded to 13 float4).
// One __syncthreads per step. Decoder h streamed to global (fire-and-forget);
// logits computed by a second, parallel kernel.
__global__ __launch_bounds__(128, 1)
void lstm_rec(const float* __restrict__ x,      // [TENC*3]
              const int*   __restrict__ y,      // [TDEC]
              const float* __restrict__ eWih,   // [400*3]
              const float* __restrict__ eWhh,   // [400*HID]
              const float* __restrict__ ebih,
              const float* __restrict__ ebhh,
              const float* __restrict__ dWih,   // [400]
              const float* __restrict__ dWhh,
              const float* __restrict__ dbih,
              const float* __restrict__ dbhh,
              float* __restrict__ hsto)         // [(TDEC-1) * HID] decoder h history
{
    __shared__ __align__(16) _Float16 hbuf[2][112];   // 100 f16 + zero pad to 13 float4

    const int t    = threadIdx.x;
    const int ln   = t & 63;
    const int cell = (t >> 6) * 50 + ln;   // wave0 -> cells 0..49, wave1 -> 50..99
    const bool wk  = (ln < 50);

    float wf[4][52];                       // packed f16 pairs, staged as float
    float wx0[4], wx1[4], wx2[4], bs[4];
    float c = 0.0f;

    if (t < 112) { hbuf[0][t] = (_Float16)0.0f; hbuf[1][t] = (_Float16)0.0f; }

    #pragma unroll
    for (int r = 0; r < 4; ++r) {
        #pragma unroll
        for (int q = 0; q < 52; ++q) wf[r][q] = 0.0f;
        wx0[r] = wx1[r] = wx2[r] = bs[r] = 0.0f;
    }
    if (wk) {
        #pragma unroll
        for (int r = 0; r < 4; ++r) {
            const int row = cell + r * HID;
            #pragma unroll
            for (int q = 0; q < 50; ++q) {
                h2_t pr;
                pr[0] = (_Float16)eWhh[row * HID + 2 * q];
                pr[1] = (_Float16)eWhh[row * HID + 2 * q + 1];
                wf[r][q] = __builtin_bit_cast(float, pr);
            }
            wx0[r] = eWih[row * 3 + 0];
            wx1[r] = eWih[row * 3 + 1];
            wx2[r] = eWih[row * 3 + 2];
            bs[r]  = ebih[row] + ebhh[row];
        }
    }
    // Pin the weight registers: opaque to the optimizer -> must stay in VGPRs,
    // cannot be rematerialized as per-step global reloads.
    #pragma unroll
    for (int r = 0; r < 4; ++r)
        #pragma unroll
        for (int q = 0; q < 52; ++q)
            asm volatile("" : "+v"(wf[r][q]));
    __syncthreads();

    int p = 0;

    // ---------------- encoder: 4096 steps ----------------
    float x0 = x[0], x1 = x[1], x2 = x[2];
    for (int s = 0; s < TENC; ++s) {
        const float cx0 = x0, cx1 = x1, cx2 = x2;
        if (s + 1 < TENC) { x0 = x[3*s+3]; x1 = x[3*s+4]; x2 = x[3*s+5]; }  // prefetch
        if (wk) {
            const float4* h4 = (const float4*)&hbuf[p][0];
            float a[4];
            #pragma unroll
            for (int r = 0; r < 4; ++r)
                a[r] = bs[r] + cx0 * wx0[r] + cx1 * wx1[r] + cx2 * wx2[r];
            #pragma unroll
            for (int q = 0; q < 13; ++q) {
                const float4 hv = h4[q];
                h2_t hh[4];
                hh[0] = __builtin_bit_cast(h2_t, hv.x);
                hh[1] = __builtin_bit_cast(h2_t, hv.y);
                hh[2] = __builtin_bit_cast(h2_t, hv.z);
                hh[3] = __builtin_bit_cast(h2_t, hv.w);
                #pragma unroll
                for (int m = 0; m < 4; ++m)
                    #pragma unroll
                    for (int r = 0; r < 4; ++r)
                        a[r] = __builtin_amdgcn_fdot2(
                            __builtin_bit_cast(h2_t, wf[r][4*q + m]), hh[m], a[r], false);
            }
            const float fi = sigm(a[0]);
            const float ff = sigm(a[1]);
            const float fg = tanh_(a[2]);
            const float fo = sigm(a[3]);
            c = ff * c + fi * fg;
            const float hn = fo * tanh_(c);
            hbuf[p ^ 1][cell] = (_Float16)hn;
        }
        __syncthreads();
        p ^= 1;
    }

    // ---------------- swap to decoder weights ----------------
    float wxd[4], bsd[4];
    #pragma unroll
    for (int r = 0; r < 4; ++r) { wxd[r] = 0.0f; bsd[r] = 0.0f; }
    if (wk) {
        #pragma unroll
        for (int r = 0; r < 4; ++r) {
            const int row = cell + r * HID;
            #pragma unroll
            for (int q = 0; q < 50; ++q) {
                h2_t pr;
                pr[0] = (_Float16)dWhh[row * HID + 2 * q];
                pr[1] = (_Float16)dWhh[row * HID + 2 * q + 1];
                wf[r][q] = __builtin_bit_cast(float, pr);
            }
            wxd[r] = dWih[row];
            bsd[r] = dbih[row] + dbhh[row];
        }
    }
    #pragma unroll
    for (int r = 0; r < 4; ++r)
        #pragma unroll
        for (int q = 0; q < 52; ++q)
            asm volatile("" : "+v"(wf[r][q]));

    // ---------------- decoder: 4095 steps (ratio==1 -> always teacher-forced) ----------------
    float yin = (float)y[0];
    for (int s = 0; s < TDEC - 1; ++s) {
        const float cin = yin;
        if (s + 2 < TDEC) yin = (float)y[s + 1];   // prefetch next label
        if (wk) {
            const float4* h4 = (const float4*)&hbuf[p][0];
            float a[4];
            #pragma unroll
            for (int r = 0; r < 4; ++r)
                a[r] = bsd[r] + cin * wxd[r];
            #pragma unroll
            for (int q = 0; q < 13; ++q) {
                const float4 hv = h4[q];
                h2_t hh[4];
                hh[0] = __builtin_bit_cast(h2_t, hv.x);
                hh[1] = __builtin_bit_cast(h2_t, hv.y);
                hh[2] = __builtin_bit_cast(h2_t, hv.z);
                hh[3] = __builtin_bit_cast(h2_t, hv.w);
                #pragma unroll
                for (int m = 0; m < 4; ++m)
                    #pragma unroll
                    for (int r = 0; r < 4; ++r)
                        a[r] = __builtin_amdgcn_fdot2(
                            __builtin_bit_cast(h2_t, wf[r][4*q + m]), hh[m], a[r], false);
            }
            const float fi = sigm(a[0]);
            const float ff = sigm(a[1]);
            const float fg = tanh_(a[2]);
            const float fo = sigm(a[3]);
            c = ff * c + fi * fg;
            const float hn = fo * tanh_(c);
            hbuf[p ^ 1][cell] = (_Float16)hn;
            hsto[s * HID + cell] = hn;             // fp32 h history; no dependent read in-kernel
        }
        __syncthreads();
        p ^= 1;
    }
}

// Parallel logits: out[t][r] = linW[r] . h_t + linb[r] for t in [0, TDEC-1),
// last row zeroed (harness poisons d_out).
__global__ __launch_bounds__(256)
void logits_k(const float* __restrict__ hsto, const float* __restrict__ linW,
              const float* __restrict__ linb, float* __restrict__ out)
{
    const int idx = blockIdx.x * 256 + threadIdx.x;
    if (idx >= TDEC * NCLS) return;
    const int tt = idx / NCLS;
    const int r  = idx % NCLS;
    if (tt >= TDEC - 1) { out[idx] = 0.0f; return; }
    const float* h  = hsto + tt * HID;
    const float* wr = linW + r * HID;
    float a = linb[r];
    #pragma unroll 4
    for (int k = 0; k < HID; ++k) a += wr[k] * h[k];
    out[idx] = a;
}

extern "C" void kernel_launch(void* const* d_in, const int* in_sizes, int n_in,
                              void* d_out, int out_size, void* d_ws, size_t ws_size,
                              hipStream_t stream)
{
    const float* x    = (const float*)d_in[0];
    const int*   y    = (const int*)  d_in[1];
    const float* eWih = (const float*)d_in[2];
    const float* eWhh = (const float*)d_in[3];
    const float* ebih = (const float*)d_in[4];
    const float* ebhh = (const float*)d_in[5];
    const float* dWih = (const float*)d_in[6];
    const float* dWhh = (const float*)d_in[7];
    const float* dbih = (const float*)d_in[8];
    const float* dbhh = (const float*)d_in[9];
    const float* linW = (const float*)d_in[10];
    const float* linb = (const float*)d_in[11];
    float* out  = (float*)d_out;
    float* hsto = (float*)d_ws;   // (TDEC-1)*HID*4 = 1.64 MB scratch

    lstm_rec<<<dim3(1), dim3(128), 0, stream>>>(
        x, y, eWih, eWhh, ebih, ebhh, dWih, dWhh, dbih, dbhh, hsto);

    const int nout = TDEC * NCLS;
    logits_k<<<dim3((nout + 255) / 256), dim3(256), 0, stream>>>(hsto, linW, linb, out);
}

// Round 4
// 4954.376 us; speedup vs baseline: 1.4770x; 1.0906x over previous
//
#include <hip/hip_runtime.h>

typedef _Float16 h2_t __attribute__((ext_vector_type(2)));

#define HID  100
#define TENC 4096
#define TDEC 4096
#define NCLS 6

__device__ __forceinline__ float sigm(float v)  { return __builtin_amdgcn_rcpf(1.0f + __expf(-v)); }
__device__ __forceinline__ float tanh_(float v) { return 1.0f - 2.0f * __builtin_amdgcn_rcpf(1.0f + __expf(2.0f * v)); }

// Persistent single-workgroup recurrence, K-SPLIT across waves.
// 256 threads = 4 waves. kh = wave>>1 selects k-half ([0,50) or [50,100)).
// Worker = lane<50; cell = (wave&1)*50 + lane. Each worker holds the 4 gate
// rows of its cell restricted to its k-half: 4 x 28 packed-f16 pairs = 112
// VGPRs -- inside the ~150-reg residency regime (R2/R3's 208-reg array
// spilled to scratch: VGPR_Count=152 vs ~250 needed => ~1000 extra cyc/step).
// Per step: read 7xds_read_b128 h-slice (broadcast), 112 fdot2, kh1 writes
// float4 partial, kh0 adds partner + bias + x, activates, owns c, writes h.
// Decoder h streamed to global; logits in a second parallel kernel.
__global__ __launch_bounds__(256, 1)
void lstm_rec(const float* __restrict__ x,      // [TENC*3]
              const int*   __restrict__ y,      // [TDEC]
              const float* __restrict__ eWih,   // [400*3]
              const float* __restrict__ eWhh,   // [400*HID]
              const float* __restrict__ ebih,
              const float* __restrict__ ebhh,
              const float* __restrict__ dWih,   // [400]
              const float* __restrict__ dWhh,
              const float* __restrict__ dbih,
              const float* __restrict__ dbhh,
              float* __restrict__ hsto)         // [(TDEC-1) * HID] decoder h history
{
    __shared__ __align__(16) _Float16 hbuf[2][2][64];  // [parity][k-half][50 used, pad 64]
    __shared__ __align__(16) float4   part4[112];      // k-half-1 partials, [cell]

    const int  t    = threadIdx.x;
    const int  wav  = t >> 6;
    const int  ln   = t & 63;
    const int  kh   = wav >> 1;              // k-half this wave computes
    const int  cell = (wav & 1) * 50 + ln;   // cell this worker's rows belong to
    const bool wk   = (ln < 50);
    const bool owner = wk && (kh == 0);      // owns c, activation, h-write
    const int  k0   = kh * 50;

    float wf[4][28];                         // packed f16 pairs: 25 real + 3 zero-pad
    float wx0[4], wx1[4], wx2[4], bs[4];
    float c = 0.0f;

    ((_Float16*)hbuf)[t] = (_Float16)0.0f;   // zero both parities incl. pads (256 entries)

    #pragma unroll
    for (int r = 0; r < 4; ++r) {
        #pragma unroll
        for (int q = 0; q < 28; ++q) wf[r][q] = 0.0f;
        wx0[r] = wx1[r] = wx2[r] = bs[r] = 0.0f;
    }
    if (wk) {
        #pragma unroll
        for (int r = 0; r < 4; ++r) {
            const int row = cell + r * HID;
            #pragma unroll
            for (int q = 0; q < 25; ++q) {
                h2_t pr;
                pr[0] = (_Float16)eWhh[row * HID + k0 + 2 * q];
                pr[1] = (_Float16)eWhh[row * HID + k0 + 2 * q + 1];
                wf[r][q] = __builtin_bit_cast(float, pr);
            }
            if (kh == 0) {                   // bias + input terms folded by the owner half
                wx0[r] = eWih[row * 3 + 0];
                wx1[r] = eWih[row * 3 + 1];
                wx2[r] = eWih[row * 3 + 2];
                bs[r]  = ebih[row] + ebhh[row];
            }
        }
    }
    #pragma unroll
    for (int r = 0; r < 4; ++r)
        #pragma unroll
        for (int q = 0; q < 28; ++q)
            asm volatile("" : "+v"(wf[r][q]));   // discourage load-sinking (fits regs now)
    __syncthreads();

    int p = 0;

    // ---------------- encoder: 4096 steps ----------------
    float x0 = x[0], x1 = x[1], x2 = x[2];
    for (int s = 0; s < TENC; ++s) {
        const float cx0 = x0, cx1 = x1, cx2 = x2;
        if (s + 1 < TENC) { x0 = x[3*s+3]; x1 = x[3*s+4]; x2 = x[3*s+5]; }
        float a[4];
        if (wk) {
            const float4* h4 = (const float4*)&hbuf[p][kh][0];
            #pragma unroll
            for (int r = 0; r < 4; ++r)
                a[r] = (kh == 0) ? (bs[r] + cx0 * wx0[r] + cx1 * wx1[r] + cx2 * wx2[r]) : 0.0f;
            #pragma unroll
            for (int q = 0; q < 7; ++q) {    // 7 x b128 = 56 f16 (50 real + 6 zero pad)
                const float4 hv = h4[q];
                h2_t hh[4];
                hh[0] = __builtin_bit_cast(h2_t, hv.x);
                hh[1] = __builtin_bit_cast(h2_t, hv.y);
                hh[2] = __builtin_bit_cast(h2_t, hv.z);
                hh[3] = __builtin_bit_cast(h2_t, hv.w);
                #pragma unroll
                for (int m = 0; m < 4; ++m)
                    #pragma unroll
                    for (int r = 0; r < 4; ++r)
                        a[r] = __builtin_amdgcn_fdot2(
                            __builtin_bit_cast(h2_t, wf[r][4*q + m]), hh[m], a[r], false);
            }
            if (kh == 1) part4[cell] = make_float4(a[0], a[1], a[2], a[3]);
        }
        __syncthreads();
        if (owner) {
            const float4 pp = part4[cell];
            const float fi = sigm(a[0] + pp.x);
            const float ff = sigm(a[1] + pp.y);
            const float fg = tanh_(a[2] + pp.z);
            const float fo = sigm(a[3] + pp.w);
            c = ff * c + fi * fg;
            const float hn = fo * tanh_(c);
            hbuf[p ^ 1][wav][ln] = (_Float16)hn;   // wave0 -> half0, wave1 -> half1
        }
        __syncthreads();
        p ^= 1;
    }

    // ---------------- swap to decoder weights ----------------
    float wxd[4], bsd[4];
    #pragma unroll
    for (int r = 0; r < 4; ++r) { wxd[r] = 0.0f; bsd[r] = 0.0f; }
    if (wk) {
        #pragma unroll
        for (int r = 0; r < 4; ++r) {
            const int row = cell + r * HID;
            #pragma unroll
            for (int q = 0; q < 25; ++q) {
                h2_t pr;
                pr[0] = (_Float16)dWhh[row * HID + k0 + 2 * q];
                pr[1] = (_Float16)dWhh[row * HID + k0 + 2 * q + 1];
                wf[r][q] = __builtin_bit_cast(float, pr);
            }
            if (kh == 0) {
                wxd[r] = dWih[row];
                bsd[r] = dbih[row] + dbhh[row];
            }
        }
    }
    #pragma unroll
    for (int r = 0; r < 4; ++r)
        #pragma unroll
        for (int q = 0; q < 28; ++q)
            asm volatile("" : "+v"(wf[r][q]));

    // ---------------- decoder: 4095 steps (ratio==1 -> always teacher-forced) ----------------
    float yin = (float)y[0];
    for (int s = 0; s < TDEC - 1; ++s) {
        const float cin = yin;
        if (s + 2 < TDEC) yin = (float)y[s + 1];
        float a[4];
        if (wk) {
            const float4* h4 = (const float4*)&hbuf[p][kh][0];
            #pragma unroll
            for (int r = 0; r < 4; ++r)
                a[r] = (kh == 0) ? (bsd[r] + cin * wxd[r]) : 0.0f;
            #pragma unroll
            for (int q = 0; q < 7; ++q) {
                const float4 hv = h4[q];
                h2_t hh[4];
                hh[0] = __builtin_bit_cast(h2_t, hv.x);
                hh[1] = __builtin_bit_cast(h2_t, hv.y);
                hh[2] = __builtin_bit_cast(h2_t, hv.z);
                hh[3] = __builtin_bit_cast(h2_t, hv.w);
                #pragma unroll
                for (int m = 0; m < 4; ++m)
                    #pragma unroll
                    for (int r = 0; r < 4; ++r)
                        a[r] = __builtin_amdgcn_fdot2(
                            __builtin_bit_cast(h2_t, wf[r][4*q + m]), hh[m], a[r], false);
            }
            if (kh == 1) part4[cell] = make_float4(a[0], a[1], a[2], a[3]);
        }
        __syncthreads();
        if (owner) {
            const float4 pp = part4[cell];
            const float fi = sigm(a[0] + pp.x);
            const float ff = sigm(a[1] + pp.y);
            const float fg = tanh_(a[2] + pp.z);
            const float fo = sigm(a[3] + pp.w);
            c = ff * c + fi * fg;
            const float hn = fo * tanh_(c);
            hbuf[p ^ 1][wav][ln] = (_Float16)hn;
            hsto[s * HID + cell] = hn;             // fp32 h history, fire-and-forget
        }
        __syncthreads();
        p ^= 1;
    }
}

// Parallel logits: out[t][r] = linW[r] . h_t + linb[r] for t in [0, TDEC-1),
// last row zeroed (harness poisons d_out).
__global__ __launch_bounds__(256)
void logits_k(const float* __restrict__ hsto, const float* __restrict__ linW,
              const float* __restrict__ linb, float* __restrict__ out)
{
    const int idx = blockIdx.x * 256 + threadIdx.x;
    if (idx >= TDEC * NCLS) return;
    const int tt = idx / NCLS;
    const int r  = idx % NCLS;
    if (tt >= TDEC - 1) { out[idx] = 0.0f; return; }
    const float* h  = hsto + tt * HID;
    const float* wr = linW + r * HID;
    float a = linb[r];
    #pragma unroll 4
    for (int k = 0; k < HID; ++k) a += wr[k] * h[k];
    out[idx] = a;
}

extern "C" void kernel_launch(void* const* d_in, const int* in_sizes, int n_in,
                              void* d_out, int out_size, void* d_ws, size_t ws_size,
                              hipStream_t stream)
{
    const float* x    = (const float*)d_in[0];
    const int*   y    = (const int*)  d_in[1];
    const float* eWih = (const float*)d_in[2];
    const float* eWhh = (const float*)d_in[3];
    const float* ebih = (const float*)d_in[4];
    const float* ebhh = (const float*)d_in[5];
    const float* dWih = (const float*)d_in[6];
    const float* dWhh = (const float*)d_in[7];
    const float* dbih = (const float*)d_in[8];
    const float* dbhh = (const float*)d_in[9];
    const float* linW = (const float*)d_in[10];
    const float* linb = (const float*)d_in[11];
    float* out  = (float*)d_out;
    float* hsto = (float*)d_ws;   // (TDEC-1)*HID*4 = 1.64 MB scratch

    lstm_rec<<<dim3(1), dim3(256), 0, stream>>>(
        x, y, eWih, eWhh, ebih, ebhh, dWih, dWhh, dbih, dbhh, hsto);

    const int nout = TDEC * NCLS;
    logits_k<<<dim3((nout + 255) / 256), dim3(256), 0, stream>>>(hsto, linW, linb, out);
}

// Round 5
// 4905.396 us; speedup vs baseline: 1.4917x; 1.0100x over previous
//
#include <hip/hip_runtime.h>

typedef _Float16 h2_t __attribute__((ext_vector_type(2)));

#define HID  100
#define TENC 4096
#define TDEC 4096
#define NCLS 6
#define NTHR 448   // 7 waves

__device__ __forceinline__ float sigm(float v)  { return __builtin_amdgcn_rcpf(1.0f + __expf(-v)); }
__device__ __forceinline__ float tanh_(float v) { return 1.0f - 2.0f * __builtin_amdgcn_rcpf(1.0f + __expf(2.0f * v)); }

// Persistent single-workgroup recurrence, v3: dense-lane k-quarter split with
// in-wave butterfly reduction and ONE barrier per step.
//   448 threads = 7 waves. lane l: ci=l&15 (cell-in-wave), kq=l>>4 (k-quarter).
//   cell = wave*16 + ci (cells 0..99 live in waves 0..6; ci>3 of wave 6 idle).
//   Each lane holds 4 gate rows x 13 packed-f16 pairs for its k-quarter
//   (52 VGPRs -- total live ~100, safely register-resident; R2-R4 proved
//   the allocator refuses >=112-reg invariant arrays: VGPR_Count 148/152/120).
//   Step: read own h-quarter from LDS (broadcast, 4 reads) -> 52 fdot2 ->
//   __shfl_xor 16/32 butterfly (same-wave, no barrier) -> all 4 kq lanes
//   redundantly activate (c replicated) -> kq0 lane writes h -> ONE barrier.
// Decoder h streamed to global; logits in a separate parallel kernel.
__global__ __launch_bounds__(NTHR, 1)
void lstm_rec(const float* __restrict__ x,      // [TENC*3]
              const int*   __restrict__ y,      // [TDEC]
              const float* __restrict__ eWih,   // [400*3]
              const float* __restrict__ eWhh,   // [400*HID]
              const float* __restrict__ ebih,
              const float* __restrict__ ebhh,
              const float* __restrict__ dWih,   // [400]
              const float* __restrict__ dWhh,
              const float* __restrict__ dbih,
              const float* __restrict__ dbhh,
              float* __restrict__ hsto)         // [(TDEC-1)*HID] decoder h history
{
    // h double-buffered as 4 zero-padded quarters of 32 f16 (64 B) each:
    // quarter q slots [0,25) = h[25q .. 25q+25), slots [25,32) stay 0 forever.
    __shared__ __align__(16) _Float16 hbuf[2][4][32];

    const int  t    = threadIdx.x;
    const int  wav  = t >> 6;
    const int  l    = t & 63;
    const int  ci   = l & 15;
    const int  kq   = l >> 4;
    const int  cell = wav * 16 + ci;
    const bool live = (cell < HID);
    const int  k0   = kq * 25;
    const int  qc   = cell / 25;            // h-write target quarter/slot
    const int  sc   = cell - qc * 25;

    float wf[4][13];                        // 13 f16 pairs per gate (pair 12 = {w[k0+24], 0})
    float wx0[4], wx1[4], wx2[4], bs[4];
    float c = 0.0f;

    // zero both parities incl. pads (2*4*32 = 256 slots)
    if (t < 256) ((_Float16*)hbuf)[t] = (_Float16)0.0f;

    #pragma unroll
    for (int r = 0; r < 4; ++r) {
        #pragma unroll
        for (int j = 0; j < 13; ++j) wf[r][j] = 0.0f;
        wx0[r] = wx1[r] = wx2[r] = bs[r] = 0.0f;
    }
    if (live) {
        #pragma unroll
        for (int r = 0; r < 4; ++r) {
            const int row = cell + r * HID;
            #pragma unroll
            for (int j = 0; j < 12; ++j) {
                h2_t pr;
                pr[0] = (_Float16)eWhh[row * HID + k0 + 2 * j];
                pr[1] = (_Float16)eWhh[row * HID + k0 + 2 * j + 1];
                wf[r][j] = __builtin_bit_cast(float, pr);
            }
            { h2_t pr; pr[0] = (_Float16)eWhh[row * HID + k0 + 24]; pr[1] = (_Float16)0.0f;
              wf[r][12] = __builtin_bit_cast(float, pr); }
            if (kq == 0) {                  // bias + input fed once, pre-butterfly
                wx0[r] = eWih[row * 3 + 0];
                wx1[r] = eWih[row * 3 + 1];
                wx2[r] = eWih[row * 3 + 2];
                bs[r]  = ebih[row] + ebhh[row];
            }
        }
    }
    #pragma unroll
    for (int r = 0; r < 4; ++r)
        #pragma unroll
        for (int j = 0; j < 13; ++j)
            asm volatile("" : "+v"(wf[r][j]));  // block load-sinking (fits regs easily now)
    __syncthreads();

    int p = 0;

    // ---------------- encoder: 4096 steps ----------------
    float x0 = x[0], x1 = x[1], x2 = x[2];
    for (int s = 0; s < TENC; ++s) {
        const float cx0 = x0, cx1 = x1, cx2 = x2;
        if (s + 1 < TENC) { x0 = x[3*s+3]; x1 = x[3*s+4]; x2 = x[3*s+5]; }

        const float4* hq = (const float4*)&hbuf[p][kq][0];
        const float4 h0 = hq[0], h1 = hq[1], h2v = hq[2];
        const float  hw12 = ((const float*)hq)[12];
        float hwv[13] = { h0.x, h0.y, h0.z, h0.w, h1.x, h1.y, h1.z, h1.w,
                          h2v.x, h2v.y, h2v.z, h2v.w, hw12 };

        float a[4];
        #pragma unroll
        for (int r = 0; r < 4; ++r)
            a[r] = (kq == 0) ? (bs[r] + cx0 * wx0[r] + cx1 * wx1[r] + cx2 * wx2[r]) : 0.0f;
        #pragma unroll
        for (int j = 0; j < 13; ++j) {
            const h2_t hh = __builtin_bit_cast(h2_t, hwv[j]);
            #pragma unroll
            for (int r = 0; r < 4; ++r)
                a[r] = __builtin_amdgcn_fdot2(__builtin_bit_cast(h2_t, wf[r][j]), hh, a[r], false);
        }
        #pragma unroll
        for (int r = 0; r < 4; ++r) {       // in-wave k-reduction (kq lanes are 16 apart)
            a[r] += __shfl_xor(a[r], 16);
            a[r] += __shfl_xor(a[r], 32);
        }
        const float fi = sigm(a[0]);
        const float ff = sigm(a[1]);
        const float fg = tanh_(a[2]);
        const float fo = sigm(a[3]);
        c = ff * c + fi * fg;               // replicated across the 4 kq lanes
        const float hn = fo * tanh_(c);
        if (kq == 0 && live) hbuf[p ^ 1][qc][sc] = (_Float16)hn;
        __syncthreads();                    // one barrier per step
        p ^= 1;
    }

    // ---------------- swap to decoder weights ----------------
    float wxd[4], bsd[4];
    #pragma unroll
    for (int r = 0; r < 4; ++r) { wxd[r] = 0.0f; bsd[r] = 0.0f; }
    if (live) {
        #pragma unroll
        for (int r = 0; r < 4; ++r) {
            const int row = cell + r * HID;
            #pragma unroll
            for (int j = 0; j < 12; ++j) {
                h2_t pr;
                pr[0] = (_Float16)dWhh[row * HID + k0 + 2 * j];
                pr[1] = (_Float16)dWhh[row * HID + k0 + 2 * j + 1];
                wf[r][j] = __builtin_bit_cast(float, pr);
            }
            { h2_t pr; pr[0] = (_Float16)dWhh[row * HID + k0 + 24]; pr[1] = (_Float16)0.0f;
              wf[r][12] = __builtin_bit_cast(float, pr); }
            if (kq == 0) {
                wxd[r] = dWih[row];
                bsd[r] = dbih[row] + dbhh[row];
            }
        }
    }
    #pragma unroll
    for (int r = 0; r < 4; ++r)
        #pragma unroll
        for (int j = 0; j < 13; ++j)
            asm volatile("" : "+v"(wf[r][j]));

    // ---------------- decoder: 4095 steps (ratio==1 -> always teacher-forced) ----------------
    float yin = (float)y[0];
    for (int s = 0; s < TDEC - 1; ++s) {
        const float cin = yin;
        if (s + 2 < TDEC) yin = (float)y[s + 1];

        const float4* hq = (const float4*)&hbuf[p][kq][0];
        const float4 h0 = hq[0], h1 = hq[1], h2v = hq[2];
        const float  hw12 = ((const float*)hq)[12];
        float hwv[13] = { h0.x, h0.y, h0.z, h0.w, h1.x, h1.y, h1.z, h1.w,
                          h2v.x, h2v.y, h2v.z, h2v.w, hw12 };

        float a[4];
        #pragma unroll
        for (int r = 0; r < 4; ++r)
            a[r] = (kq == 0) ? (bsd[r] + cin * wxd[r]) : 0.0f;
        #pragma unroll
        for (int j = 0; j < 13; ++j) {
            const h2_t hh = __builtin_bit_cast(h2_t, hwv[j]);
            #pragma unroll
            for (int r = 0; r < 4; ++r)
                a[r] = __builtin_amdgcn_fdot2(__builtin_bit_cast(h2_t, wf[r][j]), hh, a[r], false);
        }
        #pragma unroll
        for (int r = 0; r < 4; ++r) {
            a[r] += __shfl_xor(a[r], 16);
            a[r] += __shfl_xor(a[r], 32);
        }
        const float fi = sigm(a[0]);
        const float ff = sigm(a[1]);
        const float fg = tanh_(a[2]);
        const float fo = sigm(a[3]);
        c = ff * c + fi * fg;
        const float hn = fo * tanh_(c);
        if (kq == 0 && live) {
            hbuf[p ^ 1][qc][sc] = (_Float16)hn;
            hsto[s * HID + cell] = hn;      // fp32 h history, fire-and-forget
        }
        __syncthreads();
        p ^= 1;
    }
}

// Parallel logits: out[t][r] = linW[r] . h_t + linb[r] for t in [0, TDEC-1),
// last row zeroed (harness poisons d_out).
__global__ __launch_bounds__(256)
void logits_k(const float* __restrict__ hsto, const float* __restrict__ linW,
              const float* __restrict__ linb, float* __restrict__ out)
{
    const int idx = blockIdx.x * 256 + threadIdx.x;
    if (idx >= TDEC * NCLS) return;
    const int tt = idx / NCLS;
    const int r  = idx % NCLS;
    if (tt >= TDEC - 1) { out[idx] = 0.0f; return; }
    const float* h  = hsto + tt * HID;
    const float* wr = linW + r * HID;
    float a = linb[r];
    #pragma unroll 4
    for (int k = 0; k < HID; ++k) a += wr[k] * h[k];
    out[idx] = a;
}

extern "C" void kernel_launch(void* const* d_in, const int* in_sizes, int n_in,
                              void* d_out, int out_size, void* d_ws, size_t ws_size,
                              hipStream_t stream)
{
    const float* x    = (const float*)d_in[0];
    const int*   y    = (const int*)  d_in[1];
    const float* eWih = (const float*)d_in[2];
    const float* eWhh = (const float*)d_in[3];
    const float* ebih = (const float*)d_in[4];
    const float* ebhh = (const float*)d_in[5];
    const float* dWih = (const float*)d_in[6];
    const float* dWhh = (const float*)d_in[7];
    const float* dbih = (const float*)d_in[8];
    const float* dbhh = (const float*)d_in[9];
    const float* linW = (const float*)d_in[10];
    const float* linb = (const float*)d_in[11];
    float* out  = (float*)d_out;
    float* hsto = (float*)d_ws;   // (TDEC-1)*HID*4 = 1.64 MB scratch

    lstm_rec<<<dim3(1), dim3(NTHR), 0, stream>>>(
        x, y, eWih, eWhh, ebih, ebhh, dWih, dWhh, dbih, dbhh, hsto);

    const int nout = TDEC * NCLS;
    logits_k<<<dim3((nout + 255) / 256), dim3(256), 0, stream>>>(hsto, linW, linb, out);
}